// Round 1
// 666.253 us; speedup vs baseline: 1.0590x; 1.0590x over previous
//
#include <hip/hip_runtime.h>
#include <hip/hip_bf16.h>
#include <type_traits>

#define B_   2
#define L_   1024
#define DM   512
#define DI   1024
#define DS   16
#define DTR  32
#define ROWS (B_*L_)
#define NCH  32            // number of scan chunks
#define CHUNK (L_/NCH)     // 32 steps per chunk

// param-pool element offsets (bf16 pool holding all small/medium weights)
#define PO_CW    0
#define PO_CB    32768
#define PO_XPW   40960
#define PO_DTW   565248
#define PO_DTB   827392
#define PO_ALOG  835584
#define PO_DP    966656
#define PO_LNW   974848
#define PO_LNB   976896
#define PO_FNW   978944
#define PO_FNB   979456
#define PO_END   979968

#define N_WIN    (4*2097152)
#define N_WOUT   (4*1048576)
#define N_X      1048576

typedef __bf16 bf16x8 __attribute__((ext_vector_type(8)));
typedef float  f32x4  __attribute__((ext_vector_type(4)));
using bf16 = __hip_bfloat16;

__device__ __forceinline__ bf16x8 ld8(const bf16* p){
    return *reinterpret_cast<const bf16x8*>(p);
}
__device__ __forceinline__ float b2f(bf16 v){ return __bfloat162float(v); }

__device__ __forceinline__ unsigned pkbf2(float a, float b){
    bf16 ha = __float2bfloat16(a), hb = __float2bfloat16(b);
    unsigned short ua = *(unsigned short*)&ha, ub = *(unsigned short*)&hb;
    return (unsigned)ua | ((unsigned)ub << 16);
}
__device__ __forceinline__ float unpk_lo(unsigned v){
    unsigned x = v << 16; return __builtin_bit_cast(float, x);
}
__device__ __forceinline__ float unpk_hi(unsigned v){
    unsigned x = v & 0xffff0000u; return __builtin_bit_cast(float, x);
}

__device__ __forceinline__ void async_cp16(const void* g, void* s){
    __builtin_amdgcn_global_load_lds(
        (const __attribute__((address_space(1))) unsigned int*)g,
        (__attribute__((address_space(3))) unsigned int*)s, 16, 0, 0);
}

// ---------------------------------------------------------------- dtype detect
__global__ void detect_kernel(const void* Dp_raw, int* flag){
    *flag = (*(const unsigned int*)Dp_raw == 0x3F800000u) ? 1 : 0;
}

// load 8 consecutive elements from source (f32 or bf16), return packed bf16x8
__device__ __forceinline__ uint4 cv8(const void* s, long o, int f){
    union { bf16 h[8]; uint4 u; } v;
    if (f){
        const float* p = (const float*)s + o;
        float4 a = *(const float4*)p;
        float4 b = *(const float4*)(p+4);
        v.h[0]=__float2bfloat16(a.x); v.h[1]=__float2bfloat16(a.y);
        v.h[2]=__float2bfloat16(a.z); v.h[3]=__float2bfloat16(a.w);
        v.h[4]=__float2bfloat16(b.x); v.h[5]=__float2bfloat16(b.y);
        v.h[6]=__float2bfloat16(b.z); v.h[7]=__float2bfloat16(b.w);
    } else {
        v.u = *(const uint4*)((const bf16*)s + o);
    }
    return v.u;
}

// ---------------------------------------------------------------- mega convert (8 elems/thread)
// all region boundaries are multiples of 512, so a thread's 8 elements never straddle regions
__global__ void megacvt_kernel(const void* cw, const void* cb, const void* xpw,
                               const void* dtw, const void* dtb, const void* al,
                               const void* dp, const void* lnw, const void* lnb,
                               const void* fnw, const void* fnb,
                               const void* inw, const void* outw, const void* xin,
                               bf16* PP, bf16* WIN, bf16* WOUT,
                               float* X, float* R, const int* flag){
    long i = ((long)blockIdx.x*256 + threadIdx.x) * 8;
    int f = *flag;
    if (i < PO_END){
        const void* s; long o;
        if      (i < PO_CB)   { s = cw;  o = i; }
        else if (i < PO_XPW)  { s = cb;  o = i - PO_CB; }
        else if (i < PO_DTW)  { s = xpw; o = i - PO_XPW; }
        else if (i < PO_DTB)  { s = dtw; o = i - PO_DTW; }
        else if (i < PO_ALOG) { s = dtb; o = i - PO_DTB; }
        else if (i < PO_DP)   { s = al;  o = i - PO_ALOG; }
        else if (i < PO_LNW)  { s = dp;  o = i - PO_DP; }
        else if (i < PO_LNB)  { s = lnw; o = i - PO_LNW; }
        else if (i < PO_FNW)  { s = lnb; o = i - PO_LNB; }
        else if (i < PO_FNB)  { s = fnw; o = i - PO_FNW; }
        else                  { s = fnb; o = i - PO_FNB; }
        *(uint4*)&PP[i] = cv8(s, o, f);
        return;
    }
    i -= PO_END;
    if (i < N_WIN){ *(uint4*)&WIN[i] = cv8(inw, i, f); return; }
    i -= N_WIN;
    if (i < N_WOUT){
        long l = i >> 20, r = i & 1048575;
        long n = r >> 11, dir = (r >> 10) & 1, d = r & 1023;
        *(uint4*)&WOUT[i] = cv8(outw, ((l*2 + dir)*512 + n)*1024 + d, f);
        return;
    }
    i -= N_WOUT;
    if (i < N_X){
        float xv[8];
        if (f){
            *(float4*)&xv[0] = *(const float4*)((const float*)xin + i);
            *(float4*)&xv[4] = *(const float4*)((const float*)xin + i + 4);
        } else {
            union { uint4 u; bf16 h[8]; } w;
            w.u = *(const uint4*)((const bf16*)xin + i);
            #pragma unroll
            for (int j=0;j<8;++j) xv[j] = b2f(w.h[j]);
        }
        *(float4*)(X+i)   = make_float4(xv[0],xv[1],xv[2],xv[3]);
        *(float4*)(X+i+4) = make_float4(xv[4],xv[5],xv[6],xv[7]);
        float4 z = make_float4(0.f,0.f,0.f,0.f);
        *(float4*)(R+i)   = z;
        *(float4*)(R+i+4) = z;
    }
}

// ---------------------------------------------------------------- layernorm
__global__ void ln_kernel(const float* __restrict__ P, int nparts,
                          float* __restrict__ R,
                          const bf16* __restrict__ w, const bf16* __restrict__ b,
                          void* __restrict__ out, int mode, const int* flag){
    int row = blockIdx.x, lane = threadIdx.x;   // block = 64 (one wave)
    size_t base = (size_t)row*DM + lane*8;
    float v[8];
    *(float4*)&v[0] = *(const float4*)(P+base);
    *(float4*)&v[4] = *(const float4*)(P+base+4);
    for (int k=1; k<nparts; ++k){
        float4 a0 = *(const float4*)(P + (size_t)k*1048576 + base);
        float4 a1 = *(const float4*)(P + (size_t)k*1048576 + base + 4);
        v[0]+=a0.x; v[1]+=a0.y; v[2]+=a0.z; v[3]+=a0.w;
        v[4]+=a1.x; v[5]+=a1.y; v[6]+=a1.z; v[7]+=a1.w;
    }
    if (mode == 0){
        float4 r0 = *(const float4*)(R+base);
        float4 r1 = *(const float4*)(R+base+4);
        r0.x += v[0]; r0.y += v[1]; r0.z += v[2]; r0.w += v[3];
        r1.x += v[4]; r1.y += v[5]; r1.z += v[6]; r1.w += v[7];
        *(float4*)(R+base)   = r0;
        *(float4*)(R+base+4) = r1;
    } else {
        float4 r0 = *(const float4*)(R+base);
        float4 r1 = *(const float4*)(R+base+4);
        v[0]+=r0.x; v[1]+=r0.y; v[2]+=r0.z; v[3]+=r0.w;
        v[4]+=r1.x; v[5]+=r1.y; v[6]+=r1.z; v[7]+=r1.w;
    }
    float s=0.f, sq=0.f;
    #pragma unroll
    for (int j=0;j<8;++j){ s += v[j]; sq += v[j]*v[j]; }
    #pragma unroll
    for (int off=32; off>=1; off>>=1){
        s  += __shfl_xor(s,  off, 64);
        sq += __shfl_xor(sq, off, 64);
    }
    float mean = s*(1.f/DM);
    float var  = sq*(1.f/DM) - mean*mean;
    float rs   = rsqrtf(var + 1e-5f);
    bf16x8 wv = ld8(w + lane*8), bv = ld8(b + lane*8);
    float res[8];
    #pragma unroll
    for (int j=0;j<8;++j)
        res[j] = (v[j]-mean)*rs*(float)wv[j] + (float)bv[j];
    if (mode == 1 && *flag){
        float* of = (float*)out;
        *(float4*)(of+base)   = make_float4(res[0],res[1],res[2],res[3]);
        *(float4*)(of+base+4) = make_float4(res[4],res[5],res[6],res[7]);
    } else {
        union { bf16 h[8]; uint4 u; } o;
        #pragma unroll
        for (int j=0;j<8;++j) o.h[j] = __float2bfloat16(res[j]);
        *(uint4*)((bf16*)out + base) = o.u;
    }
}

// ---------------------------------------------------------------- LDS-staged GEMM (BK templated)
template<int WM, int WN, int SK, int BK, typename CT>
__global__ __launch_bounds__(WM*WN*64)
void gemm_lds(const bf16* __restrict__ A, const bf16* __restrict__ W,
              CT* __restrict__ C, int K, int lda, int ldw, int ldc,
              int selTiles, long wSel){
    constexpr int BM = WM*64, BN = WN*64, T = WM*WN*64;
    constexpr int KC = BK/8;                    // 16B chunks per row
    constexpr int RA = (BM*KC)/T, RB = (BN*KC)/T;
    __shared__ __align__(16) bf16 sA[BM*BK];
    __shared__ __align__(16) bf16 sB[BN*BK];
    int tid = threadIdx.x;
    int mtile = blockIdx.y, ntile = blockIdx.x;
    if (mtile >= selTiles) W += wSel;
    int m0 = mtile*BM, n0 = ntile*BN;
    int kPer = K/SK, kBeg = blockIdx.z*kPer, kEnd = kBeg + kPer;
    if (SK > 1)
        C += (size_t)blockIdx.z * (size_t)(gridDim.y*BM) * (size_t)(gridDim.x*BN);
    int wave = tid>>6, lane = tid&63, quad = lane>>4, r = lane&15;
    int wrow = wave / WN, wcol = wave % WN;
    const bf16* Abase = A + (size_t)m0*lda;
    const bf16* Wbase = W + (size_t)n0*ldw;
    f32x4 acc[4][4] = {};
    for (int k0 = kBeg; k0 < kEnd; k0 += BK){
        #pragma unroll
        for (int rr=0; rr<RA; ++rr){
            int q = rr*T + tid;
            int row = q/KC, cp = q%KC;
            async_cp16(Abase + (size_t)row*lda + k0 + cp*8, &sA[q*8]);
        }
        #pragma unroll
        for (int rr=0; rr<RB; ++rr){
            int q = rr*T + tid;
            int row = q/KC, cp = q%KC;
            async_cp16(Wbase + (size_t)row*ldw + k0 + cp*8, &sB[q*8]);
        }
        __syncthreads();
        #pragma unroll
        for (int ko=0; ko<BK; ko+=32){
            bf16x8 af[4], bw[4];
            #pragma unroll
            for (int mt=0; mt<4; ++mt)
                af[mt] = *(const bf16x8*)&sA[(wrow*64 + mt*16 + r)*BK + ko + quad*8];
            #pragma unroll
            for (int nt=0; nt<4; ++nt)
                bw[nt] = *(const bf16x8*)&sB[(wcol*64 + nt*16 + r)*BK + ko + quad*8];
            #pragma unroll
            for (int mt=0; mt<4; ++mt)
                #pragma unroll
                for (int nt=0; nt<4; ++nt)
                    acc[mt][nt] = __builtin_amdgcn_mfma_f32_16x16x32_bf16(
                        af[mt], bw[nt], acc[mt][nt], 0,0,0);
        }
        __syncthreads();
    }
    #pragma unroll
    for (int mt=0; mt<4; ++mt){
        #pragma unroll
        for (int nt=0; nt<4; ++nt){
            int col = n0 + wcol*64 + nt*16 + r;
            #pragma unroll
            for (int ri=0; ri<4; ++ri){
                int row = m0 + wrow*64 + mt*16 + quad*4 + ri;
                size_t idx = (size_t)row*ldc + col;
                if constexpr (std::is_same<CT, bf16>::value)
                    C[idx] = __float2bfloat16(acc[mt][nt][ri]);
                else
                    C[idx] = acc[mt][nt][ri];
            }
        }
    }
}

// ---------------------------------------------------------------- causal depthwise conv (k=4) + silu + gate pack
__global__ void conv_kernel(const bf16* __restrict__ XZ, const bf16* __restrict__ cw,
                            const bf16* __restrict__ cb, const bf16* __restrict__ Dp,
                            bf16* __restrict__ XC, unsigned* __restrict__ GU){
    int id  = blockIdx.x*256 + threadIdx.x;     // 2^21 threads
    int d   = (id & 511) * 2;
    int t   = (id >> 9) & (L_-1);
    int b   = (id >> 19) & 1;
    int dir = id >> 20;
    bf16x8 wv8 = ld8(cw + ((size_t)dir*DI + d)*4);       // taps for d (0..3) and d+1 (4..7)
    unsigned pcb = *(const unsigned*)&cb[dir*DI + d];
    float acc0 = unpk_lo(pcb), acc1 = unpk_hi(pcb);
    #pragma unroll
    for (int k=0;k<4;++k){
        int tau = t - 3 + k;
        if (tau >= 0){
            int sig = dir ? (L_-1-tau) : tau;
            unsigned pz = *(const unsigned*)&XZ[((size_t)(b*L_ + sig))*4096 + dir*2048 + d];
            acc0 += (float)wv8[k]   * unpk_lo(pz);
            acc1 += (float)wv8[4+k] * unpk_hi(pz);
        }
    }
    float u0 = acc0 * (1.f/(1.f + __expf(-acc0)));
    float u1 = acc1 * (1.f/(1.f + __expf(-acc1)));
    size_t idx = ((size_t)dir*ROWS + (size_t)b*L_ + t)*DI + d;
    *(unsigned*)&XC[idx] = pkbf2(u0, u1);
    int sig3 = dir ? (L_-1-t) : t;
    unsigned pzz = *(const unsigned*)&XZ[((size_t)(b*L_ + sig3))*4096 + dir*2048 + 1024 + d];
    float z0 = unpk_lo(pzz), z1 = unpk_hi(pzz);
    float g0 = z0*(1.f/(1.f + __expf(-z0)));
    float g1 = z1*(1.f/(1.f + __expf(-z1)));
    unsigned pdv = *(const unsigned*)&Dp[dir*DI + d];
    *(uint2*)&GU[idx] = make_uint2(pkbf2(g0, u0*unpk_lo(pdv)*g0),
                                   pkbf2(g1, u1*unpk_hi(pdv)*g1));
}

// ---------------------------------------------------------------- dt projection (fused x_proj reduce) + softplus + pack
__global__ void dtproj_kernel(const float* __restrict__ PX, const bf16* __restrict__ dtw,
                              const bf16* __restrict__ dtb, const bf16* __restrict__ XC,
                              unsigned* __restrict__ DTW, float* __restrict__ XD){
    int id  = blockIdx.x*256 + threadIdx.x;
    int d   = id & (DI-1);
    int row = (id >> 10) & (ROWS-1);
    int dir = id >> 21;
    int tid = threadIdx.x;
    int grow = dir*2048 + row;
    __shared__ float sXR[32];
    if (tid < 32){
        float s = 0.f;
        #pragma unroll
        for (int k=0;k<8;++k) s += PX[(size_t)k*262144 + (size_t)grow*64 + tid];
        sXR[tid] = s;
    } else if (tid < 64 && ((id >> 8) & 3) == 0){
        int j = tid - 32;
        float s = 0.f;
        #pragma unroll
        for (int k=0;k<8;++k) s += PX[(size_t)k*262144 + (size_t)grow*64 + 32 + j];
        XD[(size_t)row*128 + dir*64 + 32 + j] = s;
    }
    __syncthreads();
    const bf16* wp = dtw + ((size_t)dir*DI + d)*DTR;
    float acc = b2f(dtb[dir*DI + d]);
    #pragma unroll
    for (int kk=0;kk<4;++kk){
        bf16x8 wv = ld8(wp + kk*8);
        #pragma unroll
        for (int j=0;j<8;++j) acc += sXR[kk*8+j]*(float)wv[j];
    }
    float sp = acc > 20.f ? acc : log1pf(__expf(acc));
    size_t idx = ((size_t)dir*ROWS + row)*DI + d;
    float u = b2f(XC[idx]);
    DTW[idx] = pkbf2(sp, sp*u);
}

// ---------------------------------------------------------------- chunk-prefix scan (phase 2)
// one thread per (dirb, d, n) state: scans the NCH chunk (P,H) pairs,
// writing the EXCLUSIVE chunk-start state H0 for every chunk.
__global__ void scan_mid(const float* __restrict__ SP, const float* __restrict__ SH,
                         float* __restrict__ H0){
    int id   = blockIdx.x*256 + threadIdx.x;     // 65536 = 4 * DI * DS
    int dirb = id >> 14;
    int rest = id & 16383;                       // d*DS + n
    float h = 0.f;
    #pragma unroll
    for (int c=0; c<NCH; ++c){
        size_t o = ((size_t)(dirb*NCH + c) << 14) + rest;
        H0[o] = h;
        h = SP[o]*h + SH[o];
    }
}

// ---------------------------------------------------------------- selective scan v7 (3-phase)
template<int PHASE>
__global__ __launch_bounds__(256)
void scan_phase(const unsigned* __restrict__ DTW, const unsigned* __restrict__ GU,
                const float* __restrict__ XD, const bf16* __restrict__ Al,
                float* __restrict__ SP, float* __restrict__ SH,
                const float* __restrict__ H0, bf16* __restrict__ Y){
    int dirb = blockIdx.z, dir = dirb >> 1, b = dirb & 1;
    int c    = blockIdx.y;
    int d0   = blockIdx.x*128;
    int tid  = threadIdx.x;
    int dl   = tid >> 1, nh = tid & 1;
    int d    = d0 + dl;

    __shared__ __align__(16) unsigned sDTW[CHUNK*128];              // packed (dt, dt*u)
    __shared__ __align__(16) float    sBC[CHUNK][32];               // B[16] C[16]
    __shared__ __align__(16) unsigned sGU[(PHASE==3)?CHUNK*128:4];  // packed (g, u*D*g)

    const unsigned* DTWb = DTW + ((size_t)dir*ROWS + b*L_ + c*CHUNK)*DI + d0;
    #pragma unroll
    for (int it=0; it<4; ++it){
        int q = it*256 + tid;          // 0..1023 = 32 rows x 32 x 16B
        int t = q >> 5, c4 = q & 31;
        async_cp16(DTWb + (size_t)t*DI + c4*4, &sDTW[q*4]);
    }
    if (PHASE == 3){
        const unsigned* GUb = GU + ((size_t)dir*ROWS + b*L_ + c*CHUNK)*DI + d0;
        #pragma unroll
        for (int it=0; it<4; ++it){
            int q = it*256 + tid;
            int t = q >> 5, c4 = q & 31;
            async_cp16(GUb + (size_t)t*DI + c4*4, &sGU[q*4]);
        }
    }
    {
        int t = tid >> 3, j = tid & 7;  // 32 rows x 8 x 16B
        async_cp16(XD + ((size_t)(b*L_) + c*CHUNK + t)*128 + dir*64 + 32 + j*4,
                   &sBC[t][j*4]);
    }

    float An[8];
    {
        const bf16* ap = Al + ((size_t)dir*DI + d)*DS + nh*8;
        bf16x8 av = ld8(ap);
        #pragma unroll
        for (int j=0;j<8;++j) An[j] = -__expf((float)av[j]);
    }

    float h[8], pr[8];
    size_t so = ((size_t)(dirb*NCH + c)*DI + d)*DS + nh*8;
    if (PHASE == 3){
        // direct chunk-start state from the middle-kernel prefix (no lookback loop)
        f32x4 h0a = *(const f32x4*)&H0[so];
        f32x4 h0b = *(const f32x4*)&H0[so+4];
        #pragma unroll
        for (int j=0;j<4;++j){ h[j] = h0a[j]; h[4+j] = h0b[j]; }
    } else {
        #pragma unroll
        for (int j=0;j<8;++j) h[j] = 0.f;
    }
    #pragma unroll
    for (int j=0;j<8;++j) pr[j] = 1.f;
    __syncthreads();

    bf16* Yp = Y + ((size_t)b*L_ + c*CHUNK)*2048 + dir*DI + d;

    #pragma unroll 4
    for (int tl=0; tl<CHUNK; ++tl){
        unsigned dw = sDTW[tl*128 + dl];
        float dtv = unpk_lo(dw), wv = unpk_hi(dw);
        f32x4 Bv0 = *(const f32x4*)&sBC[tl][nh*8];
        f32x4 Bv1 = *(const f32x4*)&sBC[tl][nh*8+4];
        f32x4 Cv0 = *(const f32x4*)&sBC[tl][16+nh*8];
        f32x4 Cv1 = *(const f32x4*)&sBC[tl][16+nh*8+4];
        float y = 0.f;
        #pragma unroll
        for (int j=0;j<4;++j){
            float dA0 = __expf(dtv*An[j]);
            float dA1 = __expf(dtv*An[4+j]);
            h[j]   = dA0*h[j]   + wv*Bv0[j];
            h[4+j] = dA1*h[4+j] + wv*Bv1[j];
            if (PHASE == 1){ pr[j] *= dA0; pr[4+j] *= dA1; }
            else { y += h[j]*Cv0[j]; y += h[4+j]*Cv1[j]; }
        }
        if (PHASE == 3){
            y += __shfl_xor(y, 1, 64);    // add other n-half (lane pair)
            if (nh == 0){
                unsigned gu = sGU[tl*128 + dl];
                Yp[(size_t)tl*2048] = __float2bfloat16(y*unpk_lo(gu) + unpk_hi(gu));
            }
        }
    }
    if (PHASE == 1){
        *(f32x4*)&SP[so]   = *(f32x4*)&pr[0];
        *(f32x4*)&SP[so+4] = *(f32x4*)&pr[4];
        *(f32x4*)&SH[so]   = *(f32x4*)&h[0];
        *(f32x4*)&SH[so+4] = *(f32x4*)&h[4];
    }
}

// ---------------------------------------------------------------- launch
extern "C" void kernel_launch(void* const* d_in, const int* in_sizes, int n_in,
                              void* d_out, int out_size, void* d_ws, size_t ws_size,
                              hipStream_t stream){
    const void* x_raw    = d_in[0];
    const void* inw_raw  = d_in[1];
    const void* convw_raw= d_in[2];
    const void* convb_raw= d_in[3];
    const void* xpw_raw  = d_in[4];
    const void* dtw_raw  = d_in[5];
    const void* dtb_raw  = d_in[6];
    const void* alog_raw = d_in[7];
    const void* dp_raw   = d_in[8];
    const void* outw_raw = d_in[9];
    const void* lnw_raw  = d_in[10];
    const void* lnb_raw  = d_in[11];
    const void* fnw_raw  = d_in[12];
    const void* fnb_raw  = d_in[13];

    char* ws = (char*)d_ws;
    float*    X   = (float*)   (ws + 0);           //  4 MB
    float*    R   = (float*)   (ws + 4194304);     //  4 MB
    bf16*     XN  = (bf16*)    (ws + 8388608);     //  2 MB
    bf16*     XZ  = (bf16*)    (ws + 10485760);    // 16 MB
    bf16*     XC  = (bf16*)    (ws + 27262976);    //  8 MB
    float*    XD  = (float*)   (ws + 35651584);    //  1 MB
    unsigned* DTW = (unsigned*)(ws + 36700160);    // 16 MB packed (dt, dt*u)
    unsigned* GU  = (unsigned*)(ws + 52428800);    // 16 MB packed (g, u*D*g)
    bf16*     Y   = (bf16*)    (ws + 68157440);    //  8 MB
    float*    SP  = (float*)   (ws + 76546048);    //  8 MB
    float*    SH  = (float*)   (ws + 84934656);    //  8 MB
    bf16*     PP  = (bf16*)    (ws + 93323264);    //  2 MB
    bf16*     WIN = (bf16*)    (ws + 95420416);    // 16 MB
    bf16*     WOUT= (bf16*)    (ws + 112197632);   //  8 MB
    float*    PX  = (float*)   (ws + 120586240);   //  8 MB
    float*    PO  = (float*)   (ws + 128974848);   // 16 MB
    int*      FLAG= (int*)     (ws + 145752064);   //  4 B
    float*    H0  = (float*)   (ws + 145752128);   //  8 MB exclusive chunk-start states
    // total ~147 MB (ws = 256 MiB)

    detect_kernel<<<1,1,0,stream>>>(dp_raw, FLAG);
    {
        long total = ((long)PO_END + N_WIN + N_WOUT + N_X) / 8;
        int blocks = (int)((total + 255)/256);
        megacvt_kernel<<<blocks,256,0,stream>>>(
            convw_raw, convb_raw, xpw_raw, dtw_raw, dtb_raw, alog_raw, dp_raw,
            lnw_raw, lnb_raw, fnw_raw, fnb_raw, inw_raw, outw_raw, x_raw,
            PP, WIN, WOUT, X, R, FLAG);
    }

    for (int l=0; l<4; ++l){
        ln_kernel<<<ROWS,64,0,stream>>>(l==0 ? X : PO, l==0 ? 1 : 4, R,
                                        PP+PO_LNW+l*DM, PP+PO_LNB+l*DM, XN, 0, FLAG);

        // in_proj: (2048x512) @ (4096x512)^T -> XZ bf16
        gemm_lds<2,2,1,64,bf16><<<dim3(32,16,1),256,0,stream>>>(
            XN, WIN + (size_t)l*2097152, XZ, 512, 512, 512, 4096, 1<<30, 0);

        conv_kernel<<<8192,256,0,stream>>>(XZ, PP+PO_CW + (size_t)l*2*DI*4,
                                           PP+PO_CB + l*2*DI, PP+PO_DP + l*2*DI,
                                           XC, GU);

        // x_proj: dirs folded along M (XC is dir-major 4096x1024), N=64, split-K=8
        gemm_lds<2,1,8,64,float><<<dim3(1,32,8),128,0,stream>>>(
            XC, PP+PO_XPW + (size_t)l*2*64*DI, PX, 1024, 1024, 1024, 64,
            16, (long)64*DI);

        // dt proj (fused split-K reduce) + B/C reduce into XD
        dtproj_kernel<<<16384,256,0,stream>>>(PX, PP+PO_DTW + (size_t)l*2*DI*DTR,
                                              PP+PO_DTB + l*2*DI, XC, DTW, XD);

        scan_phase<1><<<dim3(DI/128,NCH,4),256,0,stream>>>(
            DTW, GU, XD, PP+PO_ALOG + (size_t)l*2*DI*DS, SP, SH, H0, Y);
        scan_mid<<<256,256,0,stream>>>(SP, SH, H0);
        scan_phase<3><<<dim3(DI/128,NCH,4),256,0,stream>>>(
            DTW, GU, XD, PP+PO_ALOG + (size_t)l*2*DI*DS, SP, SH, H0, Y);

        // out_proj fused K=2048 (packed W), split-K=4 -> PO partials
        gemm_lds<2,2,4,64,float><<<dim3(4,16,4),256,0,stream>>>(
            Y, WOUT + (size_t)l*1048576, PO, 2048, 2048, 2048, 512, 1<<30, 0);
    }

    ln_kernel<<<ROWS,64,0,stream>>>(PO, 4, R, PP+PO_FNW, PP+PO_FNB, d_out, 1, FLAG);
}